// Round 1
// 542.916 us; speedup vs baseline: 1.1475x; 1.1475x over previous
//
#include <hip/hip_runtime.h>

#define CC 16
#define GG 300

typedef unsigned int  u32;
typedef unsigned short u16;

// ---- bf16 pack/unpack (workspace is bf16-packed; inputs/outputs are f32) ----
__device__ __forceinline__ float bf_lo(u32 u) { union { u32 i; float f; } v; v.i = u << 16;          return v.f; }
__device__ __forceinline__ float bf_hi(u32 u) { union { u32 i; float f; } v; v.i = u & 0xffff0000u;  return v.f; }
__device__ __forceinline__ u16 f2bf(float f) {   // round-to-nearest-even
    union { float f; u32 i; } v; v.f = f;
    u32 r = v.i + 0x7fffu + ((v.i >> 16) & 1u);
    return (u16)(r >> 16);
}

// -------- transpose+quantize: (i,c,y,x) f32 -> (i,y,x,c) bf16-packed --------
__global__ void transpose_planes_k(const float* __restrict__ src, u32* __restrict__ dst) {
    int tid = blockIdx.x * blockDim.x + threadIdx.x;
    const int total = 3 * GG * GG;
    if (tid >= total) return;
    int x = tid % GG;
    int y = (tid / GG) % GG;
    int i = tid / (GG * GG);
    u32 packed[8];
#pragma unroll
    for (int h = 0; h < 8; ++h) {
        float a = src[((size_t)(i * CC + 2 * h)     * GG + y) * GG + x];
        float b = src[((size_t)(i * CC + 2 * h + 1) * GG + y) * GG + x];
        packed[h] = (u32)f2bf(a) | ((u32)f2bf(b) << 16);
    }
    uint4* d = (uint4*)(dst + (size_t)tid * 8);   // 32B per (i,y,x) corner
    d[0] = make_uint4(packed[0], packed[1], packed[2], packed[3]);
    d[1] = make_uint4(packed[4], packed[5], packed[6], packed[7]);
}

__global__ void transpose_lines_k(const float* __restrict__ src, u32* __restrict__ dst) {
    int tid = blockIdx.x * blockDim.x + threadIdx.x;
    const int total = 3 * GG;
    if (tid >= total) return;
    int g = tid % GG;
    int i = tid / GG;
    u32 packed[8];
#pragma unroll
    for (int h = 0; h < 8; ++h) {
        float a = src[(size_t)(i * CC + 2 * h)     * GG + g];
        float b = src[(size_t)(i * CC + 2 * h + 1) * GG + g];
        packed[h] = (u32)f2bf(a) | ((u32)f2bf(b) << 16);
    }
    uint4* d = (uint4*)(dst + (size_t)tid * 8);
    d[0] = make_uint4(packed[0], packed[1], packed[2], packed[3]);
    d[1] = make_uint4(packed[4], packed[5], packed[6], packed[7]);
}

__device__ __forceinline__ float bilerp(float v00, float v01, float v10, float v11,
                                        float wx, float wy) {
    float ox = 1.0f - wx, oy = 1.0f - wy;
    return (v00 * ox + v01 * wx) * oy + (v10 * ox + v11 * wx) * wy;
}

// ---------------- plane-phased sampling kernel ----------------
// Each block handles ONE plane for a chunk of points. Blocks are plane-major
// (all plane-0 blocks first), so at any instant each XCD works on ~one plane
// whose bf16 table (2.88 MB) fits in the 4 MiB per-XCD L2 -> corner reads hit L2.
// xyz is loaded nontemporal so the streaming read doesn't evict the plane.
__global__ __launch_bounds__(256) void sample_plane_k(
    const float* __restrict__ xyz,      // (N,3) f32
    const u32* __restrict__ planesT,    // (3,G,G,C) bf16-packed, 8 u32 per corner
    const u32* __restrict__ linesT,     // (3,G,C) bf16-packed
    float* __restrict__ out, int N, int nbPer)   // (3C, N) f32
{
    const int plane = blockIdx.x / nbPer;                 // 0,1,2 (wave-uniform)
    const int n = (blockIdx.x % nbPer) * 256 + threadIdx.x;
    if (n >= N) return;

    float crd[3];
    crd[0] = __builtin_nontemporal_load(xyz + 3 * (size_t)n + 0);
    crd[1] = __builtin_nontemporal_load(xyz + 3 * (size_t)n + 1);
    crd[2] = __builtin_nontemporal_load(xyz + 3 * (size_t)n + 2);

    int i0[3], i1[3];
    float w[3];
#pragma unroll
    for (int k = 0; k < 3; ++k) {
        // ref: x = (coord + 1.0) * 0.5 * (size-1); x0 = clip(floor(x),0,size-1)
        float xk = (crd[k] + 1.0f) * 0.5f * (float)(GG - 1);
        float xf = floorf(xk);
        xf = fminf(fmaxf(xf, 0.0f), (float)(GG - 1));
        i0[k] = (int)xf;
        i1[k] = min(i0[k] + 1, GG - 1);
        w[k] = xk - xf;
    }

    const int mata[3] = {1, 0, 0};   // gx axis (x / W of plane)
    const int matb[3] = {2, 2, 1};   // gy axis (y / H of plane)
    const int a = mata[plane];       // plane is uniform -> scalar selects
    const int b = matb[plane];

    const int xa0 = i0[a], xa1 = i1[a];
    const int yb0 = i0[b], yb1 = i1[b];
    const float wx = w[a], wy = w[b], wz = w[plane];
    const float oz = 1.0f - wz;

    const u32* pb = planesT + (size_t)plane * (GG * GG * 8);
    const uint4* c00 = (const uint4*)(pb + (size_t)(yb0 * GG + xa0) * 8);
    const uint4* c01 = (const uint4*)(pb + (size_t)(yb0 * GG + xa1) * 8);
    const uint4* c10 = (const uint4*)(pb + (size_t)(yb1 * GG + xa0) * 8);
    const uint4* c11 = (const uint4*)(pb + (size_t)(yb1 * GG + xa1) * 8);
    const uint4* lp0 = (const uint4*)(linesT + ((size_t)plane * GG + i0[plane]) * 8);
    const uint4* lp1 = (const uint4*)(linesT + ((size_t)plane * GG + i1[plane]) * 8);

    uint4 A00 = c00[0], B00 = c00[1];
    uint4 A01 = c01[0], B01 = c01[1];
    uint4 A10 = c10[0], B10 = c10[1];
    uint4 A11 = c11[0], B11 = c11[1];
    uint4 AL0 = lp0[0], BL0 = lp0[1];
    uint4 AL1 = lp1[0], BL1 = lp1[1];

    u32 r00[8] = {A00.x, A00.y, A00.z, A00.w, B00.x, B00.y, B00.z, B00.w};
    u32 r01[8] = {A01.x, A01.y, A01.z, A01.w, B01.x, B01.y, B01.z, B01.w};
    u32 r10[8] = {A10.x, A10.y, A10.z, A10.w, B10.x, B10.y, B10.z, B10.w};
    u32 r11[8] = {A11.x, A11.y, A11.z, A11.w, B11.x, B11.y, B11.z, B11.w};
    u32 rl0[8] = {AL0.x, AL0.y, AL0.z, AL0.w, BL0.x, BL0.y, BL0.z, BL0.w};
    u32 rl1[8] = {AL1.x, AL1.y, AL1.z, AL1.w, BL1.x, BL1.y, BL1.z, BL1.w};

#pragma unroll
    for (int u = 0; u < 8; ++u) {   // u32 u holds channels 2u (lo) and 2u+1 (hi)
        float p0 = bilerp(bf_lo(r00[u]), bf_lo(r01[u]), bf_lo(r10[u]), bf_lo(r11[u]), wx, wy);
        float p1 = bilerp(bf_hi(r00[u]), bf_hi(r01[u]), bf_hi(r10[u]), bf_hi(r11[u]), wx, wy);
        float l0 = bf_lo(rl0[u]) * oz + bf_lo(rl1[u]) * wz;
        float l1 = bf_hi(rl0[u]) * oz + bf_hi(rl1[u]) * wz;
        size_t row = (size_t)(plane * CC + 2 * u);
        __builtin_nontemporal_store(p0 * l0, &out[row * (size_t)N + n]);
        __builtin_nontemporal_store(p1 * l1, &out[(row + 1) * (size_t)N + n]);
    }
}

// ---------------- fallback: direct f32 sampling from (3,C,G,G) ----------------
__global__ __launch_bounds__(256) void sample_fallback_k(
    const float* __restrict__ xyz,
    const float* __restrict__ planes,    // (3,C,G,G) f32
    const float* __restrict__ lines,     // (3,C,G) f32
    float* __restrict__ out, int N)
{
    int n = blockIdx.x * blockDim.x + threadIdx.x;
    if (n >= N) return;

    float crd[3];
    crd[0] = xyz[3 * n + 0];
    crd[1] = xyz[3 * n + 1];
    crd[2] = xyz[3 * n + 2];

    int i0[3], i1[3];
    float w[3];
#pragma unroll
    for (int k = 0; k < 3; ++k) {
        float xk = (crd[k] + 1.0f) * 0.5f * (float)(GG - 1);
        float xf = floorf(xk);
        xf = fminf(fmaxf(xf, 0.0f), (float)(GG - 1));
        i0[k] = (int)xf;
        i1[k] = min(i0[k] + 1, GG - 1);
        w[k] = xk - xf;
    }

    const int mata[3] = {1, 0, 0};
    const int matb[3] = {2, 2, 1};

    for (int i = 0; i < 3; ++i) {
        const int xa0 = i0[mata[i]], xa1 = i1[mata[i]];
        const int yb0 = i0[matb[i]], yb1 = i1[matb[i]];
        const float wx = w[mata[i]], wy = w[matb[i]], wz = w[i];
        const float oz = 1.0f - wz;
        const float* pb = planes + (size_t)i * (CC * GG * GG);
        const float* lb = lines + (size_t)i * (CC * GG);
        for (int c = 0; c < CC; ++c) {
            const float* pc = pb + (size_t)c * (GG * GG);
            float p = bilerp(pc[yb0 * GG + xa0], pc[yb0 * GG + xa1],
                             pc[yb1 * GG + xa0], pc[yb1 * GG + xa1], wx, wy);
            float l = lb[c * GG + i0[i]] * oz + lb[c * GG + i1[i]] * wz;
            out[(size_t)(i * CC + c) * (size_t)N + n] = p * l;
        }
    }
}

extern "C" void kernel_launch(void* const* d_in, const int* in_sizes, int n_in,
                              void* d_out, int out_size, void* d_ws, size_t ws_size,
                              hipStream_t stream) {
    const float* xyz    = (const float*)d_in[0];   // (N,3) f32
    const float* planes = (const float*)d_in[1];   // (3,C,G,G) f32
    const float* lines  = (const float*)d_in[2];   // (3,C,G) f32
    float* out = (float*)d_out;                    // (3C, N) f32
    const int N = in_sizes[0] / 3;

    const size_t planesT_u32 = (size_t)3 * GG * GG * 8;   // 2,160,000 u32 = 8.64 MB
    const size_t linesT_u32  = (size_t)3 * GG * 8;        // 7,200 u32
    const size_t need = (planesT_u32 + linesT_u32) * sizeof(u32);

    if (ws_size >= need) {
        u32* planesT = (u32*)d_ws;
        u32* linesT  = planesT + planesT_u32;   // byte off 8,640,000 -> 32B aligned
        {
            int total = 3 * GG * GG;
            transpose_planes_k<<<(total + 255) / 256, 256, 0, stream>>>(planes, planesT);
        }
        {
            int total = 3 * GG;
            transpose_lines_k<<<(total + 255) / 256, 256, 0, stream>>>(lines, linesT);
        }
        int nbPer = (N + 255) / 256;
        sample_plane_k<<<3 * nbPer, 256, 0, stream>>>(xyz, planesT, linesT, out, N, nbPer);
    } else {
        sample_fallback_k<<<(N + 255) / 256, 256, 0, stream>>>(xyz, planes, lines, out, N);
    }
}

// Round 2
// 512.754 us; speedup vs baseline: 1.2150x; 1.0588x over previous
//
#include <hip/hip_runtime.h>

#define CC 16
#define GG 300

typedef unsigned int  u32;
typedef unsigned short u16;

// ---- bf16 pack/unpack (workspace is bf16-packed; inputs/outputs are f32) ----
__device__ __forceinline__ float bf_lo(u32 u) { union { u32 i; float f; } v; v.i = u << 16;          return v.f; }
__device__ __forceinline__ float bf_hi(u32 u) { union { u32 i; float f; } v; v.i = u & 0xffff0000u;  return v.f; }
__device__ __forceinline__ u16 f2bf(float f) {   // round-to-nearest-even
    union { float f; u32 i; } v; v.f = f;
    u32 r = v.i + 0x7fffu + ((v.i >> 16) & 1u);
    return (u16)(r >> 16);
}

// -------- transpose+quantize: (i,c,y,x) f32 -> (i,y,x,c) bf16-packed --------
__global__ void transpose_planes_k(const float* __restrict__ src, u32* __restrict__ dst) {
    int tid = blockIdx.x * blockDim.x + threadIdx.x;
    const int total = 3 * GG * GG;
    if (tid >= total) return;
    int x = tid % GG;
    int y = (tid / GG) % GG;
    int i = tid / (GG * GG);
    u32 packed[8];
#pragma unroll
    for (int h = 0; h < 8; ++h) {
        float a = src[((size_t)(i * CC + 2 * h)     * GG + y) * GG + x];
        float b = src[((size_t)(i * CC + 2 * h + 1) * GG + y) * GG + x];
        packed[h] = (u32)f2bf(a) | ((u32)f2bf(b) << 16);
    }
    uint4* d = (uint4*)(dst + (size_t)tid * 8);   // 32B per (i,y,x) corner
    d[0] = make_uint4(packed[0], packed[1], packed[2], packed[3]);
    d[1] = make_uint4(packed[4], packed[5], packed[6], packed[7]);
}

__global__ void transpose_lines_k(const float* __restrict__ src, u32* __restrict__ dst) {
    int tid = blockIdx.x * blockDim.x + threadIdx.x;
    const int total = 3 * GG;
    if (tid >= total) return;
    int g = tid % GG;
    int i = tid / GG;
    u32 packed[8];
#pragma unroll
    for (int h = 0; h < 8; ++h) {
        float a = src[(size_t)(i * CC + 2 * h)     * GG + g];
        float b = src[(size_t)(i * CC + 2 * h + 1) * GG + g];
        packed[h] = (u32)f2bf(a) | ((u32)f2bf(b) << 16);
    }
    uint4* d = (uint4*)(dst + (size_t)tid * 8);
    d[0] = make_uint4(packed[0], packed[1], packed[2], packed[3]);
    d[1] = make_uint4(packed[4], packed[5], packed[6], packed[7]);
}

__device__ __forceinline__ float bilerp(float v00, float v01, float v10, float v11,
                                        float wx, float wy) {
    float ox = 1.0f - wx, oy = 1.0f - wy;
    return (v00 * ox + v01 * wx) * oy + (v10 * ox + v11 * wx) * wy;
}

// ---------------- plane-phased, lane-paired sampling kernel ----------------
// Blocks are plane-major (all plane-0 blocks first) so each XCD's 4 MiB L2
// holds the active plane (2.88 MB bf16) -> corner reads are L2 hits.
// TWO lanes per point (channel halves 0-7 / 8-15): the pair's two 16B corner
// loads are adjacent addresses in the SAME instruction -> TA coalesces them
// into one 64B-line request, halving corner transactions (the bottleneck).
// The line table (9.6 KB/plane) is staged in LDS, removing its 4 divergent
// loads from the TA path entirely.
__global__ __launch_bounds__(256) void sample_pair_k(
    const float* __restrict__ xyz,      // (N,3) f32
    const u32* __restrict__ planesT,    // (3,G,G,C) bf16-packed, 8 u32 per corner
    const u32* __restrict__ linesT,     // (3,G,C) bf16-packed
    float* __restrict__ out, int N, int nbPer)   // (3C, N) f32
{
    __shared__ uint4 lineLds[GG * 2];   // 300 rows x 32B = 9600 B

    const int plane = blockIdx.x / nbPer;                 // 0,1,2 (wave-uniform)

    // stage this plane's line table into LDS (coalesced)
    const uint4* lsrc = (const uint4*)(linesT + (size_t)plane * (GG * 8));
    for (int idx = threadIdx.x; idx < GG * 2; idx += 256)
        lineLds[idx] = lsrc[idx];
    __syncthreads();

    const int t = (blockIdx.x % nbPer) * 256 + (int)threadIdx.x;
    const int p = t >> 1;              // point index (shared by lane pair)
    const int h = t & 1;               // channel half: 0 -> ch0-7, 1 -> ch8-15
    if (p >= N) return;

    const float cx = __builtin_nontemporal_load(xyz + 3 * (size_t)p + 0);
    const float cy = __builtin_nontemporal_load(xyz + 3 * (size_t)p + 1);
    const float cz = __builtin_nontemporal_load(xyz + 3 * (size_t)p + 2);

    // per-axis lerp indices (scalars, no runtime-indexed arrays -> no scratch)
    int i0x, i1x, i0y, i1y, i0z, i1z;
    float wxa, wya, wza;
    {
        float xk = (cx + 1.0f) * 0.5f * (float)(GG - 1);
        float xf = fminf(fmaxf(floorf(xk), 0.0f), (float)(GG - 1));
        i0x = (int)xf; i1x = min(i0x + 1, GG - 1); wxa = xk - xf;
    }
    {
        float xk = (cy + 1.0f) * 0.5f * (float)(GG - 1);
        float xf = fminf(fmaxf(floorf(xk), 0.0f), (float)(GG - 1));
        i0y = (int)xf; i1y = min(i0y + 1, GG - 1); wya = xk - xf;
    }
    {
        float xk = (cz + 1.0f) * 0.5f * (float)(GG - 1);
        float xf = fminf(fmaxf(floorf(xk), 0.0f), (float)(GG - 1));
        i0z = (int)xf; i1z = min(i0z + 1, GG - 1); wza = xk - xf;
    }

    // mata = {1,0,0}  (gx axis), matb = {2,2,1}  (gy axis), line axis = plane
    const int   xa0 = (plane == 0) ? i0y : i0x;
    const int   xa1 = (plane == 0) ? i1y : i1x;
    const int   yb0 = (plane == 2) ? i0y : i0z;
    const int   yb1 = (plane == 2) ? i1y : i1z;
    const float wx  = (plane == 0) ? wya : wxa;
    const float wy  = (plane == 2) ? wya : wza;
    const int   l0i = (plane == 0) ? i0x : ((plane == 1) ? i0y : i0z);
    const int   l1i = (plane == 0) ? i1x : ((plane == 1) ? i1y : i1z);
    const float wz  = (plane == 0) ? wxa : ((plane == 1) ? wya : wza);
    const float oz  = 1.0f - wz;

    const u32* pb = planesT + (size_t)plane * (GG * GG * 8);
    // each lane loads its 16B channel-half of each 32B corner; the pair's
    // two halves coalesce into one 64B-line transaction per instruction
    const uint4 q00 = *((const uint4*)(pb + (size_t)(yb0 * GG + xa0) * 8) + h);
    const uint4 q01 = *((const uint4*)(pb + (size_t)(yb0 * GG + xa1) * 8) + h);
    const uint4 q10 = *((const uint4*)(pb + (size_t)(yb1 * GG + xa0) * 8) + h);
    const uint4 q11 = *((const uint4*)(pb + (size_t)(yb1 * GG + xa1) * 8) + h);
    const uint4 ql0 = lineLds[l0i * 2 + h];
    const uint4 ql1 = lineLds[l1i * 2 + h];

    const u32 a00[4] = {q00.x, q00.y, q00.z, q00.w};
    const u32 a01[4] = {q01.x, q01.y, q01.z, q01.w};
    const u32 a10[4] = {q10.x, q10.y, q10.z, q10.w};
    const u32 a11[4] = {q11.x, q11.y, q11.z, q11.w};
    const u32 al0[4] = {ql0.x, ql0.y, ql0.z, ql0.w};
    const u32 al1[4] = {ql1.x, ql1.y, ql1.z, ql1.w};

    const size_t rowbase = (size_t)(plane * CC + 8 * h);
#pragma unroll
    for (int u = 0; u < 4; ++u) {   // u32 u holds channels 8h+2u (lo), 8h+2u+1 (hi)
        float plo = bilerp(bf_lo(a00[u]), bf_lo(a01[u]), bf_lo(a10[u]), bf_lo(a11[u]), wx, wy);
        float phi = bilerp(bf_hi(a00[u]), bf_hi(a01[u]), bf_hi(a10[u]), bf_hi(a11[u]), wx, wy);
        float llo = bf_lo(al0[u]) * oz + bf_lo(al1[u]) * wz;
        float lhi = bf_hi(al0[u]) * oz + bf_hi(al1[u]) * wz;
        __builtin_nontemporal_store(plo * llo, &out[(rowbase + 2 * u)     * (size_t)N + p]);
        __builtin_nontemporal_store(phi * lhi, &out[(rowbase + 2 * u + 1) * (size_t)N + p]);
    }
}

// ---------------- fallback: direct f32 sampling from (3,C,G,G) ----------------
__global__ __launch_bounds__(256) void sample_fallback_k(
    const float* __restrict__ xyz,
    const float* __restrict__ planes,    // (3,C,G,G) f32
    const float* __restrict__ lines,     // (3,C,G) f32
    float* __restrict__ out, int N)
{
    int n = blockIdx.x * blockDim.x + threadIdx.x;
    if (n >= N) return;

    float crd[3];
    crd[0] = xyz[3 * n + 0];
    crd[1] = xyz[3 * n + 1];
    crd[2] = xyz[3 * n + 2];

    int i0[3], i1[3];
    float w[3];
#pragma unroll
    for (int k = 0; k < 3; ++k) {
        float xk = (crd[k] + 1.0f) * 0.5f * (float)(GG - 1);
        float xf = floorf(xk);
        xf = fminf(fmaxf(xf, 0.0f), (float)(GG - 1));
        i0[k] = (int)xf;
        i1[k] = min(i0[k] + 1, GG - 1);
        w[k] = xk - xf;
    }

    const int mata[3] = {1, 0, 0};
    const int matb[3] = {2, 2, 1};

    for (int i = 0; i < 3; ++i) {
        const int xa0 = i0[mata[i]], xa1 = i1[mata[i]];
        const int yb0 = i0[matb[i]], yb1 = i1[matb[i]];
        const float wx = w[mata[i]], wy = w[matb[i]], wz = w[i];
        const float oz = 1.0f - wz;
        const float* pb = planes + (size_t)i * (CC * GG * GG);
        const float* lb = lines + (size_t)i * (CC * GG);
        for (int c = 0; c < CC; ++c) {
            const float* pc = pb + (size_t)c * (GG * GG);
            float p = bilerp(pc[yb0 * GG + xa0], pc[yb0 * GG + xa1],
                             pc[yb1 * GG + xa0], pc[yb1 * GG + xa1], wx, wy);
            float l = lb[c * GG + i0[i]] * oz + lb[c * GG + i1[i]] * wz;
            out[(size_t)(i * CC + c) * (size_t)N + n] = p * l;
        }
    }
}

extern "C" void kernel_launch(void* const* d_in, const int* in_sizes, int n_in,
                              void* d_out, int out_size, void* d_ws, size_t ws_size,
                              hipStream_t stream) {
    const float* xyz    = (const float*)d_in[0];   // (N,3) f32
    const float* planes = (const float*)d_in[1];   // (3,C,G,G) f32
    const float* lines  = (const float*)d_in[2];   // (3,C,G) f32
    float* out = (float*)d_out;                    // (3C, N) f32
    const int N = in_sizes[0] / 3;

    const size_t planesT_u32 = (size_t)3 * GG * GG * 8;   // 2,160,000 u32 = 8.64 MB
    const size_t linesT_u32  = (size_t)3 * GG * 8;        // 7,200 u32
    const size_t need = (planesT_u32 + linesT_u32) * sizeof(u32);

    if (ws_size >= need) {
        u32* planesT = (u32*)d_ws;
        u32* linesT  = planesT + planesT_u32;   // byte off 8,640,000 -> 32B aligned
        {
            int total = 3 * GG * GG;
            transpose_planes_k<<<(total + 255) / 256, 256, 0, stream>>>(planes, planesT);
        }
        {
            int total = 3 * GG;
            transpose_lines_k<<<(total + 255) / 256, 256, 0, stream>>>(lines, linesT);
        }
        // two lanes per point -> 2N threads per plane
        int nbPer = (int)(((size_t)2 * N + 255) / 256);
        sample_pair_k<<<3 * nbPer, 256, 0, stream>>>(xyz, planesT, linesT, out, N, nbPer);
    } else {
        sample_fallback_k<<<(N + 255) / 256, 256, 0, stream>>>(xyz, planes, lines, out, N);
    }
}